// Round 9
// baseline (599.144 us; speedup 1.0000x reference)
//
#include <hip/hip_runtime.h>
#include <hip/hip_bf16.h>
#include <stdint.h>

typedef _Float16 f16;
typedef _Float16 f16x8 __attribute__((ext_vector_type(8)));
typedef _Float16 f16x4 __attribute__((ext_vector_type(4)));
typedef float f32x4 __attribute__((ext_vector_type(4)));
typedef float f32x16 __attribute__((ext_vector_type(16)));

#define T_TOK 8192
#define H_DIM 1024
#define NHEAD 8
#define V_DIM 2048

// global -> LDS direct load, 16B per lane. LDS dest = wave-uniform base + lane*16.
__device__ __forceinline__ void gload16(const void* g, void* l) {
  __builtin_amdgcn_global_load_lds(
      (const __attribute__((address_space(1))) void*)(uintptr_t)g,
      (__attribute__((address_space(3))) void*)(unsigned)(uintptr_t)l,
      16, 0, 0);
}

__device__ __forceinline__ float fast_tanh(float x) {
  float xc = fminf(fmaxf(x, -12.f), 12.f);
  float e = __expf(2.f * xc);
  return (e - 1.f) / (e + 1.f);
}

// Stage one half-tile (128 rows x 64 f16 = 16KB) with 2 global_load_lds.
__device__ __forceinline__ void stage_half(const f16* __restrict__ gRowBase,
                                           char* ldsHalf, int tid, int sl8,
                                           int Kd) {
  const int srow = tid >> 3;
  char* wuni = ldsHalf + ((tid >> 6) << 10);  // wave-uniform base
  gload16(gRowBase + (size_t)srow * Kd + sl8, wuni);
  gload16(gRowBase + (size_t)(srow + 64) * Kd + sl8, wuni + 8192);
}

// ---------- 256x256x64 pipelined 4-phase GEMM, 32x32x16 MFMA ----------
// [R4-proven 1.83 PF — inner loop untouched since R4]
template <int TANH, int NMAJ>
__global__ __launch_bounds__(512, 2) void k_gemm(const f16* __restrict__ A,
                                                 const f16* __restrict__ Bt,
                                                 const float* __restrict__ bias,
                                                 f16* __restrict__ C,
                                                 int M, int N, int K) {
  __shared__ __align__(16) f16 sA[2][16384];
  __shared__ __align__(16) f16 sB[2][16384];
  const int tid = threadIdx.x;
  const int lane = tid & 63;
  const int wid = tid >> 6;
  const int wr = wid >> 2, wc = wid & 3;
  const int gx = gridDim.x, gy = gridDim.y;
  const int id = blockIdx.y * gx + blockIdx.x;
  const int cpx = (gx * gy) >> 3;
  const int sw = (id & 7) * cpx + (id >> 3);
  int m0, n0;
  if (NMAJ) {
    n0 = (sw / gy) * 256;
    m0 = (sw % gy) * 256;
  } else {
    m0 = (sw / gx) * 256;
    n0 = (sw % gx) * 256;
  }
  const int NT = K >> 6;  // NT even (K % 128 == 0)
  const int sl8 = ((tid & 7) ^ ((tid >> 3) & 7)) << 3;  // staging src col (f16)
  const int rr31 = lane & 31;   // A/B fragment row (m or n within 32)
  const int hi = lane >> 5;     // k-half selector
  const int l7 = lane & 7;      // row&7 for XOR slot swizzle

  const f16* Ag = A + (size_t)m0 * K;
  const f16* Bg = Bt + (size_t)n0 * K;
  char* sAb = (char*)&sA[0][0];
  char* sBb = (char*)&sB[0][0];

  // prologue: tile0 A+B -> buf0, tile1 B -> buf1
  stage_half(Ag, sAb, tid, sl8, K);
  stage_half(Ag + (size_t)128 * K, sAb + 16384, tid, sl8, K);
  stage_half(Bg, sBb, tid, sl8, K);
  stage_half(Bg + (size_t)128 * K, sBb + 16384, tid, sl8, K);
  stage_half(Bg + 64, sBb + 32768, tid, sl8, K);
  stage_half(Bg + (size_t)128 * K + 64, sBb + 32768 + 16384, tid, sl8, K);
  asm volatile("s_waitcnt vmcnt(4)" ::: "memory");  // tile0 A+B resident
  __builtin_amdgcn_s_barrier();
  __builtin_amdgcn_sched_barrier(0);

  f32x16 acc[4][2] = {};
  f16x8 af0[4], af1[4], bf[2][4];

#define LDA_SET(dst, base, q)                                                  \
  {                                                                            \
    _Pragma("unroll") for (int mi = 0; mi < 4; ++mi) {                         \
      dst[mi] = *(const f16x8*)((base) + wr * 16384 + mi * 4096 + rr31 * 128 + \
                                (((2 * (q) + hi) ^ l7) << 4));                 \
    }                                                                          \
  }
#define LDB(base)                                                              \
  {                                                                            \
    _Pragma("unroll") for (int n = 0; n < 2; ++n) {                            \
      _Pragma("unroll") for (int ks = 0; ks < 4; ++ks) {                       \
        bf[n][ks] = *(const f16x8*)((base) + wc * 8192 + n * 4096 +            \
                                    rr31 * 128 + (((2 * ks + hi) ^ l7) << 4)); \
      }                                                                        \
    }                                                                          \
  }
#define MFMA8(ks, S)                                                           \
  {                                                                            \
    __builtin_amdgcn_s_setprio(1);                                             \
    _Pragma("unroll") for (int mi = 0; mi < 4; ++mi) {                         \
      _Pragma("unroll") for (int n = 0; n < 2; ++n) {                          \
        acc[mi][n] = __builtin_amdgcn_mfma_f32_32x32x16_f16(                   \
            S[mi], bf[n][ks], acc[mi][n], 0, 0, 0);                            \
      }                                                                        \
    }                                                                          \
    __builtin_amdgcn_s_setprio(0);                                             \
  }

  // preload k-step 0 fragments of tile 0
  LDA_SET(af0, sAb, 0);

#define HALF(tt, bc)                                                           \
  {                                                                            \
    const char* cA = sAb + (bc)*32768;                                         \
    const char* cB = sBb + (bc)*32768;                                         \
    char* nA = sAb + ((bc) ^ 1) * 32768;                                       \
    char* nB = sBb + (bc)*32768;                                               \
    const int ktA = ((tt) + 1) << 6, ktB = ((tt) + 2) << 6;                    \
    const bool doA = (tt) + 1 < NT, doB = (tt) + 2 < NT;                       \
    /* ph0 */                                                                  \
    if (doA) stage_half(Ag + ktA, nA, tid, sl8, K);                            \
    LDB(cB);                                                                   \
    LDA_SET(af1, cA, 1);                                                       \
    __builtin_amdgcn_sched_barrier(0);                                         \
    MFMA8(0, af0);                                                             \
    __builtin_amdgcn_s_barrier();                                              \
    /* ph1 */                                                                  \
    if (doA) stage_half(Ag + (size_t)128 * K + ktA, nA + 16384, tid, sl8, K);  \
    LDA_SET(af0, cA, 2);                                                       \
    __builtin_amdgcn_sched_barrier(0);                                         \
    MFMA8(1, af1);                                                             \
    __builtin_amdgcn_s_barrier();                                              \
    /* ph2 */                                                                  \
    if (doB) stage_half(Bg + ktB, nB, tid, sl8, K);                            \
    LDA_SET(af1, cA, 3);                                                       \
    __builtin_amdgcn_sched_barrier(0);                                         \
    MFMA8(2, af0);                                                             \
    __builtin_amdgcn_s_barrier();                                              \
    /* ph3: counted vmcnt; preload next tile ks0 after barrier */              \
    if (doB) stage_half(Bg + (size_t)128 * K + ktB, nB + 16384, tid, sl8, K);  \
    if (doB) {                                                                 \
      asm volatile("s_waitcnt vmcnt(4)" ::: "memory");                         \
    } else {                                                                   \
      asm volatile("s_waitcnt vmcnt(0)" ::: "memory");                         \
    }                                                                          \
    __builtin_amdgcn_s_barrier();                                              \
    __builtin_amdgcn_sched_barrier(0);                                         \
    if (doA) LDA_SET(af0, sAb + ((bc) ^ 1) * 32768, 0);                        \
    __builtin_amdgcn_sched_barrier(0);                                         \
    MFMA8(3, af1);                                                             \
  }

#pragma unroll 1
  for (int T = 0; T < NT; T += 2) {
    HALF(T, 0);
    HALF(T + 1, 1);
  }
#undef HALF
#undef LDA_SET
#undef LDB
#undef MFMA8

  // epilogue: 32x32 D layout: col = lane&31, row = (reg&3) + 8*(reg>>2) + 4*hi
  const int ccol0 = n0 + wc * 64 + rr31;
  float bv[2];
#pragma unroll
  for (int n = 0; n < 2; ++n) bv[n] = bias[ccol0 + n * 32];
#pragma unroll
  for (int mi = 0; mi < 4; ++mi) {
#pragma unroll
    for (int rq = 0; rq < 4; ++rq) {
#pragma unroll
      for (int r2 = 0; r2 < 4; ++r2) {
        const int row = m0 + wr * 128 + mi * 32 + r2 + 8 * rq + 4 * hi;
        f16* Crow = C + (size_t)row * N;
#pragma unroll
        for (int n = 0; n < 2; ++n) {
          float v = acc[mi][n][rq * 4 + r2] + bv[n];
          if (TANH) v = fast_tanh(v);
          Crow[ccol0 + n * 32] = (f16)v;
        }
      }
    }
  }
}

// ---------- fp32 [R][C] -> fp16 [C][R] transpose-convert, 64x64 tiles -------
__global__ __launch_bounds__(256) void k_transpose(const float* __restrict__ in,
                                                   f16* __restrict__ out,
                                                   int R, int C) {
  __shared__ f16 tile[64][66];
  const int c0 = blockIdx.x * 64, r0 = blockIdx.y * 64;
  const int tid = threadIdx.x;
  const int tr = tid >> 4;          // 0..15
  const int tc4 = (tid & 15) * 4;   // 0..60
#pragma unroll
  for (int i = 0; i < 4; ++i) {
    const int r = tr + i * 16;
    const float4 v = *(const float4*)&in[(size_t)(r0 + r) * C + c0 + tc4];
    tile[tc4 + 0][r] = (f16)v.x;
    tile[tc4 + 1][r] = (f16)v.y;
    tile[tc4 + 2][r] = (f16)v.z;
    tile[tc4 + 3][r] = (f16)v.w;
  }
  __syncthreads();
  const int oc = tid >> 2;          // 0..63
  const int or4 = (tid & 3) * 16;   // 0,16,32,48
#pragma unroll
  for (int i = 0; i < 4; ++i) {
    f16x4 w;
    w[0] = tile[oc][or4 + i * 4 + 0];
    w[1] = tile[oc][or4 + i * 4 + 1];
    w[2] = tile[oc][or4 + i * 4 + 2];
    w[3] = tile[oc][or4 + i * 4 + 3];
    *(f16x4*)&out[(size_t)(c0 + oc) * R + r0 + or4 + i * 4] = w;
  }
}

// ---------- fused prior + hidden->f16 convert (one pass over hidden) --------
// Warp per token: reads the 4KB row once (float4, coalesced), writes f16 row,
// accumulates the 8 prior dot-products, sigmoid+renorm on lane 0.
__global__ __launch_bounds__(256) void k_prior_conv(const float* __restrict__ hidden,
                                                    const float* __restrict__ pw,
                                                    const float* __restrict__ pb,
                                                    float* __restrict__ prior,
                                                    f16* __restrict__ hidden_h) {
  const int wid = threadIdx.x >> 6, lane = threadIdx.x & 63;
  const int t = blockIdx.x * 4 + wid;
  const float* hrow = hidden + (size_t)t * H_DIM;
  f16* orow = hidden_h + (size_t)t * H_DIM;
  float acc[NHEAD] = {0.f, 0.f, 0.f, 0.f, 0.f, 0.f, 0.f, 0.f};
#pragma unroll
  for (int i = 0; i < 4; ++i) {
    const int k = i * 256 + lane * 4;
    const float4 v = *(const float4*)(hrow + k);
    f16x4 o;
    o[0] = (f16)v.x; o[1] = (f16)v.y; o[2] = (f16)v.z; o[3] = (f16)v.w;
    *(f16x4*)(orow + k) = o;
    const float vv[4] = {v.x, v.y, v.z, v.w};
#pragma unroll
    for (int j = 0; j < 4; ++j) {
      const float* wr = pw + (size_t)(k + j) * NHEAD;
#pragma unroll
      for (int h = 0; h < NHEAD; ++h) acc[h] += vv[j] * wr[h];
    }
  }
#pragma unroll
  for (int h = 0; h < NHEAD; ++h) {
#pragma unroll
    for (int off = 32; off >= 1; off >>= 1) acc[h] += __shfl_xor(acc[h], off);
  }
  if (lane == 0) {
    float p[NHEAD], s = 0.f;
#pragma unroll
    for (int h = 0; h < NHEAD; ++h) {
      p[h] = 1.f / (1.f + __expf(-(acc[h] + pb[h])));
      s += p[h];
    }
    float inv = 1.f / (s + 1e-8f);
#pragma unroll
    for (int h = 0; h < NHEAD; ++h) prior[t * NHEAD + h] = p[h] * inv;
  }
}

// ---------- wave-per-token softmax (no max pass, no barriers, no LDS) -------
// Lane covers v = lane*32..lane*32+31. Per head: 4 coalesced f16x8 loads
// (64B/lane), exp, 6-shuffle wave reduce, scale-accumulate. Next head's loads
// hand-prefetched (ping-pong regs) so HBM latency hides under exp/combine.
__global__ __launch_bounds__(256) void k_softmax(const f16* __restrict__ logits,
                                                 const float* __restrict__ prior,
                                                 float* __restrict__ out) {
  const int wid = threadIdx.x >> 6, lane = threadIdx.x & 63;
  const int t = blockIdx.x * 4 + wid;
  const f16* base = logits + (size_t)t * NHEAD * V_DIM + lane * 32;

  float oa[32];
#pragma unroll
  for (int j = 0; j < 32; ++j) oa[j] = 0.f;

  f16x8 cx0 = *(const f16x8*)(base + 0);
  f16x8 cx1 = *(const f16x8*)(base + 8);
  f16x8 cx2 = *(const f16x8*)(base + 16);
  f16x8 cx3 = *(const f16x8*)(base + 24);

#pragma unroll 1
  for (int h = 0; h < NHEAD; ++h) {
    const int hn = (h < NHEAD - 1) ? h + 1 : h;  // last iter: reload (discarded)
    const f16* nb = base + (size_t)hn * V_DIM;
    f16x8 nx0 = *(const f16x8*)(nb + 0);
    f16x8 nx1 = *(const f16x8*)(nb + 8);
    f16x8 nx2 = *(const f16x8*)(nb + 16);
    f16x8 nx3 = *(const f16x8*)(nb + 24);

    float e[32];
    float s = 0.f;
#pragma unroll
    for (int j = 0; j < 8; ++j) e[j] = __expf(fminf((float)cx0[j], 50.f));
#pragma unroll
    for (int j = 0; j < 8; ++j) e[8 + j] = __expf(fminf((float)cx1[j], 50.f));
#pragma unroll
    for (int j = 0; j < 8; ++j) e[16 + j] = __expf(fminf((float)cx2[j], 50.f));
#pragma unroll
    for (int j = 0; j < 8; ++j) e[24 + j] = __expf(fminf((float)cx3[j], 50.f));
#pragma unroll
    for (int j = 0; j < 32; ++j) s += e[j];
#pragma unroll
    for (int off = 32; off >= 1; off >>= 1) s += __shfl_xor(s, off);
    const float coef = prior[t * NHEAD + h] / s;
#pragma unroll
    for (int j = 0; j < 32; ++j) oa[j] += coef * e[j];
    cx0 = nx0; cx1 = nx1; cx2 = nx2; cx3 = nx3;
  }

  float4* op = (float4*)(out + (size_t)t * V_DIM + lane * 32);
#pragma unroll
  for (int j = 0; j < 8; ++j)
    op[j] = make_float4(oa[4 * j], oa[4 * j + 1], oa[4 * j + 2], oa[4 * j + 3]);
}

extern "C" void kernel_launch(void* const* d_in, const int* in_sizes, int n_in,
                              void* d_out, int out_size, void* d_ws, size_t ws_size,
                              hipStream_t stream) {
  const float* hidden   = (const float*)d_in[0];
  const float* prior_w  = (const float*)d_in[1];
  const float* prior_b  = (const float*)d_in[2];
  const float* latent_w = (const float*)d_in[3];
  const float* latent_b = (const float*)d_in[4];
  const float* output_w = (const float*)d_in[5];
  const float* output_b = (const float*)d_in[6];
  float* out = (float*)d_out;

  char* ws = (char*)d_ws;
  size_t off = 0;
  auto alloc = [&](size_t bytes) -> void* {
    void* p = ws + off;
    off += (bytes + 255) & ~(size_t)255;
    return p;
  };
  f16* hidden_h = (f16*)alloc((size_t)T_TOK * H_DIM * 2);          // [8192][1024]
  f16* lw_t     = (f16*)alloc((size_t)NHEAD * H_DIM * H_DIM * 2);  // [8192][1024]
  f16* ow_t     = (f16*)alloc((size_t)V_DIM * H_DIM * 2);          // [2048][1024]
  float* prior  = (float*)alloc((size_t)T_TOK * NHEAD * 4);

  // tc=8192 (R6: per-work GEMM 2x faster at large grids; R4: ws fits)
  int tc = T_TOK;
  while (tc > 256) {
    size_t need = off + (size_t)tc * NHEAD * H_DIM * 2 + 256 +
                  (size_t)tc * NHEAD * V_DIM * 2 + 256;
    if (need <= ws_size) break;
    tc >>= 1;
  }
  f16* latent_h = (f16*)alloc((size_t)tc * NHEAD * H_DIM * 2);  // [tc*8][1024]
  f16* logits_h = (f16*)alloc((size_t)tc * NHEAD * V_DIM * 2);  // [tc*8][2048]

  // prep passes
  k_prior_conv<<<T_TOK / 4, 256, 0, stream>>>(hidden, prior_w, prior_b, prior,
                                              hidden_h);
  k_transpose<<<dim3(NHEAD * H_DIM / 64, H_DIM / 64), 256, 0, stream>>>(
      latent_w, lw_t, H_DIM, NHEAD * H_DIM);
  k_transpose<<<dim3(V_DIM / 64, H_DIM / 64), 256, 0, stream>>>(
      output_w, ow_t, H_DIM, V_DIM);

  const int nchunk = T_TOK / tc;
  for (int c = 0; c < nchunk; ++c) {
    const f16* Ah = hidden_h + (size_t)c * tc * H_DIM;
    // GEMM1: latent = tanh(hidden @ latent_w + b), n-major XCD swizzle
    k_gemm<1, 1><<<dim3(NHEAD * H_DIM / 256, tc / 256), 512, 0, stream>>>(
        Ah, lw_t, latent_b, latent_h, tc, NHEAD * H_DIM, H_DIM);
    // GEMM2 split into two M-halves (visibility: drops top-5 threshold to
    // ~78us so G1/softmax surface in the profile; cost ~= 1 dispatch boundary)
    const int MH = tc * NHEAD / 2;
    for (int s = 0; s < 2; ++s) {
      k_gemm<0, 0><<<dim3(V_DIM / 256, MH / 256), 512, 0, stream>>>(
          latent_h + (size_t)s * MH * H_DIM, ow_t, output_b,
          logits_h + (size_t)s * MH * V_DIM, MH, V_DIM, H_DIM);
    }
    // wave-per-token softmax + prior-weighted combine
    k_softmax<<<tc / 4, 256, 0, stream>>>(logits_h,
                                          prior + (size_t)c * tc * NHEAD,
                                          out + (size_t)c * tc * V_DIM);
  }
}

// Round 11
// 597.927 us; speedup vs baseline: 1.0020x; 1.0020x over previous
//
#include <hip/hip_runtime.h>
#include <hip/hip_bf16.h>
#include <stdint.h>

typedef _Float16 f16;
typedef _Float16 f16x8 __attribute__((ext_vector_type(8)));
typedef _Float16 f16x4 __attribute__((ext_vector_type(4)));
typedef float f32x4 __attribute__((ext_vector_type(4)));
typedef float f32x16 __attribute__((ext_vector_type(16)));

#define T_TOK 8192
#define H_DIM 1024
#define NHEAD 8
#define V_DIM 2048

// global -> LDS direct load, 16B per lane. LDS dest = wave-uniform base + lane*16.
__device__ __forceinline__ void gload16(const void* g, void* l) {
  __builtin_amdgcn_global_load_lds(
      (const __attribute__((address_space(1))) void*)(uintptr_t)g,
      (__attribute__((address_space(3))) void*)(unsigned)(uintptr_t)l,
      16, 0, 0);
}

__device__ __forceinline__ float fast_tanh(float x) {
  float xc = fminf(fmaxf(x, -12.f), 12.f);
  float e = __expf(2.f * xc);
  return (e - 1.f) / (e + 1.f);
}

// Stage one half-tile (128 rows x 64 f16 = 16KB) with 2 global_load_lds.
__device__ __forceinline__ void stage_half(const f16* __restrict__ gRowBase,
                                           char* ldsHalf, int tid, int sl8,
                                           int Kd) {
  const int srow = tid >> 3;
  char* wuni = ldsHalf + ((tid >> 6) << 10);  // wave-uniform base
  gload16(gRowBase + (size_t)srow * Kd + sl8, wuni);
  gload16(gRowBase + (size_t)(srow + 64) * Kd + sl8, wuni + 8192);
}

// ---------- 256x256x64 pipelined 4-phase GEMM, 32x32x16 MFMA ----------
// [proven 0.92 PF, bytes unchanged since R6]
// Grid (8, M/256, NS): 8 n-tiles per 2048-col strip, NS strips. Per strip:
// m-major XCD swizzle -> B-strip (4 MiB) L2-resident per XCD.
template <int TANH>
__global__ __launch_bounds__(512, 2) void k_gemm(const f16* __restrict__ A,
                                                 const f16* __restrict__ Bt,
                                                 const float* __restrict__ bias,
                                                 f16* __restrict__ C,
                                                 int M, int N, int K) {
  __shared__ __align__(16) f16 sA[2][16384];
  __shared__ __align__(16) f16 sB[2][16384];
  const int tid = threadIdx.x;
  const int lane = tid & 63;
  const int wid = tid >> 6;
  const int wr = wid >> 2, wc = wid & 3;
  const int id = blockIdx.y * 8 + blockIdx.x;
  const int cpx = gridDim.y;  // blocks per XCD within a strip
  const int sw = (id & 7) * cpx + (id >> 3);
  const int m0 = (sw >> 3) * 256;
  const int n0 = blockIdx.z * 2048 + (sw & 7) * 256;
  const int NT = K >> 6;  // NT even (K % 128 == 0)
  const int sl8 = ((tid & 7) ^ ((tid >> 3) & 7)) << 3;  // staging src col (f16)
  const int rr31 = lane & 31;   // A/B fragment row (m or n within 32)
  const int hi = lane >> 5;     // k-half selector
  const int l7 = lane & 7;      // row&7 for XOR slot swizzle

  const f16* Ag = A + (size_t)m0 * K;
  const f16* Bg = Bt + (size_t)n0 * K;
  char* sAb = (char*)&sA[0][0];
  char* sBb = (char*)&sB[0][0];

  // prologue: tile0 A+B -> buf0, tile1 B -> buf1
  stage_half(Ag, sAb, tid, sl8, K);
  stage_half(Ag + (size_t)128 * K, sAb + 16384, tid, sl8, K);
  stage_half(Bg, sBb, tid, sl8, K);
  stage_half(Bg + (size_t)128 * K, sBb + 16384, tid, sl8, K);
  stage_half(Bg + 64, sBb + 32768, tid, sl8, K);
  stage_half(Bg + (size_t)128 * K + 64, sBb + 32768 + 16384, tid, sl8, K);
  asm volatile("s_waitcnt vmcnt(4)" ::: "memory");  // tile0 A+B resident
  __builtin_amdgcn_s_barrier();
  __builtin_amdgcn_sched_barrier(0);

  f32x16 acc[4][2] = {};
  f16x8 af0[4], af1[4], bf[2][4];

#define LDA_SET(dst, base, q)                                                  \
  {                                                                            \
    _Pragma("unroll") for (int mi = 0; mi < 4; ++mi) {                         \
      dst[mi] = *(const f16x8*)((base) + wr * 16384 + mi * 4096 + rr31 * 128 + \
                                (((2 * (q) + hi) ^ l7) << 4));                 \
    }                                                                          \
  }
#define LDB(base)                                                              \
  {                                                                            \
    _Pragma("unroll") for (int n = 0; n < 2; ++n) {                            \
      _Pragma("unroll") for (int ks = 0; ks < 4; ++ks) {                       \
        bf[n][ks] = *(const f16x8*)((base) + wc * 8192 + n * 4096 +            \
                                    rr31 * 128 + (((2 * ks + hi) ^ l7) << 4)); \
      }                                                                        \
    }                                                                          \
  }
#define MFMA8(ks, S)                                                           \
  {                                                                            \
    __builtin_amdgcn_s_setprio(1);                                             \
    _Pragma("unroll") for (int mi = 0; mi < 4; ++mi) {                         \
      _Pragma("unroll") for (int n = 0; n < 2; ++n) {                          \
        acc[mi][n] = __builtin_amdgcn_mfma_f32_32x32x16_f16(                   \
            S[mi], bf[n][ks], acc[mi][n], 0, 0, 0);                            \
      }                                                                        \
    }                                                                          \
    __builtin_amdgcn_s_setprio(0);                                             \
  }

  // preload k-step 0 fragments of tile 0
  LDA_SET(af0, sAb, 0);

#define HALF(tt, bc)                                                           \
  {                                                                            \
    const char* cA = sAb + (bc)*32768;                                         \
    const char* cB = sBb + (bc)*32768;                                         \
    char* nA = sAb + ((bc) ^ 1) * 32768;                                       \
    char* nB = sBb + (bc)*32768;                                               \
    const int ktA = ((tt) + 1) << 6, ktB = ((tt) + 2) << 6;                    \
    const bool doA = (tt) + 1 < NT, doB = (tt) + 2 < NT;                       \
    /* ph0 */                                                                  \
    if (doA) stage_half(Ag + ktA, nA, tid, sl8, K);                            \
    LDB(cB);                                                                   \
    LDA_SET(af1, cA, 1);                                                       \
    __builtin_amdgcn_sched_barrier(0);                                         \
    MFMA8(0, af0);                                                             \
    __builtin_amdgcn_s_barrier();                                              \
    /* ph1 */                                                                  \
    if (doA) stage_half(Ag + (size_t)128 * K + ktA, nA + 16384, tid, sl8, K);  \
    LDA_SET(af0, cA, 2);                                                       \
    __builtin_amdgcn_sched_barrier(0);                                         \
    MFMA8(1, af1);                                                             \
    __builtin_amdgcn_s_barrier();                                              \
    /* ph2 */                                                                  \
    if (doB) stage_half(Bg + ktB, nB, tid, sl8, K);                            \
    LDA_SET(af1, cA, 3);                                                       \
    __builtin_amdgcn_sched_barrier(0);                                         \
    MFMA8(2, af0);                                                             \
    __builtin_amdgcn_s_barrier();                                              \
    /* ph3: counted vmcnt; preload next tile ks0 after barrier */              \
    if (doB) stage_half(Bg + (size_t)128 * K + ktB, nB + 16384, tid, sl8, K);  \
    if (doB) {                                                                 \
      asm volatile("s_waitcnt vmcnt(4)" ::: "memory");                         \
    } else {                                                                   \
      asm volatile("s_waitcnt vmcnt(0)" ::: "memory");                         \
    }                                                                          \
    __builtin_amdgcn_s_barrier();                                              \
    __builtin_amdgcn_sched_barrier(0);                                         \
    if (doA) LDA_SET(af0, sAb + ((bc) ^ 1) * 32768, 0);                        \
    __builtin_amdgcn_sched_barrier(0);                                         \
    MFMA8(3, af1);                                                             \
  }

#pragma unroll 1
  for (int T = 0; T < NT; T += 2) {
    HALF(T, 0);
    HALF(T + 1, 1);
  }
#undef HALF
#undef LDA_SET
#undef LDB
#undef MFMA8

  // epilogue: 32x32 D layout: col = lane&31, row = (reg&3) + 8*(reg>>2) + 4*hi
  const int ccol0 = n0 + wc * 64 + rr31;
  float bv[2];
#pragma unroll
  for (int n = 0; n < 2; ++n) bv[n] = bias[ccol0 + n * 32];
#pragma unroll
  for (int mi = 0; mi < 4; ++mi) {
#pragma unroll
    for (int rq = 0; rq < 4; ++rq) {
#pragma unroll
      for (int r2 = 0; r2 < 4; ++r2) {
        const int row = m0 + wr * 128 + mi * 32 + r2 + 8 * rq + 4 * hi;
        f16* Crow = C + (size_t)row * N;
#pragma unroll
        for (int n = 0; n < 2; ++n) {
          float v = acc[mi][n][rq * 4 + r2] + bv[n];
          if (TANH) v = fast_tanh(v);
          Crow[ccol0 + n * 32] = (f16)v;
        }
      }
    }
  }
}

// ---------- fp32 [R][C] -> fp16 [C][R] transpose-convert, 64x64 tiles -------
__global__ __launch_bounds__(256) void k_transpose(const float* __restrict__ in,
                                                   f16* __restrict__ out,
                                                   int R, int C) {
  __shared__ f16 tile[64][66];
  const int c0 = blockIdx.x * 64, r0 = blockIdx.y * 64;
  const int tid = threadIdx.x;
  const int tr = tid >> 4;          // 0..15
  const int tc4 = (tid & 15) * 4;   // 0..60
#pragma unroll
  for (int i = 0; i < 4; ++i) {
    const int r = tr + i * 16;
    const float4 v = *(const float4*)&in[(size_t)(r0 + r) * C + c0 + tc4];
    tile[tc4 + 0][r] = (f16)v.x;
    tile[tc4 + 1][r] = (f16)v.y;
    tile[tc4 + 2][r] = (f16)v.z;
    tile[tc4 + 3][r] = (f16)v.w;
  }
  __syncthreads();
  const int oc = tid >> 2;          // 0..63
  const int or4 = (tid & 3) * 16;   // 0,16,32,48
#pragma unroll
  for (int i = 0; i < 4; ++i) {
    f16x4 w;
    w[0] = tile[oc][or4 + i * 4 + 0];
    w[1] = tile[oc][or4 + i * 4 + 1];
    w[2] = tile[oc][or4 + i * 4 + 2];
    w[3] = tile[oc][or4 + i * 4 + 3];
    *(f16x4*)&out[(size_t)(c0 + oc) * R + r0 + or4 + i * 4] = w;
  }
}

// ---------- fused prior + hidden->f16 convert (one pass over hidden) --------
__global__ __launch_bounds__(256) void k_prior_conv(const float* __restrict__ hidden,
                                                    const float* __restrict__ pw,
                                                    const float* __restrict__ pb,
                                                    float* __restrict__ prior,
                                                    f16* __restrict__ hidden_h) {
  const int wid = threadIdx.x >> 6, lane = threadIdx.x & 63;
  const int t = blockIdx.x * 4 + wid;
  const float* hrow = hidden + (size_t)t * H_DIM;
  f16* orow = hidden_h + (size_t)t * H_DIM;
  float acc[NHEAD] = {0.f, 0.f, 0.f, 0.f, 0.f, 0.f, 0.f, 0.f};
#pragma unroll
  for (int i = 0; i < 4; ++i) {
    const int k = i * 256 + lane * 4;
    const float4 v = *(const float4*)(hrow + k);
    f16x4 o;
    o[0] = (f16)v.x; o[1] = (f16)v.y; o[2] = (f16)v.z; o[3] = (f16)v.w;
    *(f16x4*)(orow + k) = o;
    const float vv[4] = {v.x, v.y, v.z, v.w};
#pragma unroll
    for (int j = 0; j < 4; ++j) {
      const float* wr = pw + (size_t)(k + j) * NHEAD;
#pragma unroll
      for (int h = 0; h < NHEAD; ++h) acc[h] += vv[j] * wr[h];
    }
  }
#pragma unroll
  for (int h = 0; h < NHEAD; ++h) {
#pragma unroll
    for (int off = 32; off >= 1; off >>= 1) acc[h] += __shfl_xor(acc[h], off);
  }
  if (lane == 0) {
    float p[NHEAD], s = 0.f;
#pragma unroll
    for (int h = 0; h < NHEAD; ++h) {
      p[h] = 1.f / (1.f + __expf(-(acc[h] + pb[h])));
      s += p[h];
    }
    float inv = 1.f / (s + 1e-8f);
#pragma unroll
    for (int h = 0; h < NHEAD; ++h) prior[t * NHEAD + h] = p[h] * inv;
  }
}

// ---------- block-per-token softmax (no max pass), chunk-local logits -------
__global__ __launch_bounds__(256) void k_softmax(const f16* __restrict__ logits,
                                                 const float* __restrict__ prior,
                                                 float* __restrict__ out,
                                                 int t0) {
  __shared__ float redsm[NHEAD * 4];
  const int tl = blockIdx.x;        // chunk-local token
  const int t = t0 + tl;            // global token
  const int tid = threadIdx.x, lane = tid & 63, wid = tid >> 6;
  const f16* base = logits + (size_t)tl * NHEAD * V_DIM + tid * 8;

  f16x8 x[NHEAD];
#pragma unroll
  for (int h = 0; h < NHEAD; ++h) x[h] = *(const f16x8*)(base + h * V_DIM);

  float xv[NHEAD][8];
  float sml[NHEAD];
#pragma unroll
  for (int h = 0; h < NHEAD; ++h) {
    float s = 0.f;
#pragma unroll
    for (int j = 0; j < 8; ++j) {
      xv[h][j] = __expf(fminf((float)x[h][j], 50.f));
      s += xv[h][j];
    }
    sml[h] = s;
  }
#pragma unroll
  for (int h = 0; h < NHEAD; ++h) {
#pragma unroll
    for (int off = 32; off >= 1; off >>= 1) sml[h] += __shfl_xor(sml[h], off);
  }
  if (lane == 0) {
#pragma unroll
    for (int h = 0; h < NHEAD; ++h) redsm[h * 4 + wid] = sml[h];
  }
  __syncthreads();

  float oa[8] = {0.f, 0.f, 0.f, 0.f, 0.f, 0.f, 0.f, 0.f};
#pragma unroll
  for (int h = 0; h < NHEAD; ++h) {
    const float s = redsm[h * 4 + 0] + redsm[h * 4 + 1] + redsm[h * 4 + 2] +
                    redsm[h * 4 + 3];
    const float coef = prior[t * NHEAD + h] / s;
#pragma unroll
    for (int j = 0; j < 8; ++j) oa[j] += coef * xv[h][j];
  }
  float4* op = (float4*)(out + (size_t)t * V_DIM + tid * 8);
  op[0] = make_float4(oa[0], oa[1], oa[2], oa[3]);
  op[1] = make_float4(oa[4], oa[5], oa[6], oa[7]);
}

extern "C" void kernel_launch(void* const* d_in, const int* in_sizes, int n_in,
                              void* d_out, int out_size, void* d_ws, size_t ws_size,
                              hipStream_t stream) {
  const float* hidden   = (const float*)d_in[0];
  const float* prior_w  = (const float*)d_in[1];
  const float* prior_b  = (const float*)d_in[2];
  const float* latent_w = (const float*)d_in[3];
  const float* latent_b = (const float*)d_in[4];
  const float* output_w = (const float*)d_in[5];
  const float* output_b = (const float*)d_in[6];
  float* out = (float*)d_out;

  char* ws = (char*)d_ws;
  size_t off = 0;
  auto alloc = [&](size_t bytes) -> void* {
    void* p = ws + off;
    off += (bytes + 255) & ~(size_t)255;
    return p;
  };
  f16* hidden_h = (f16*)alloc((size_t)T_TOK * H_DIM * 2);          // 16 MiB
  f16* lw_t     = (f16*)alloc((size_t)NHEAD * H_DIM * H_DIM * 2);  // 16 MiB
  f16* ow_t     = (f16*)alloc((size_t)V_DIM * H_DIM * 2);          // 4 MiB
  float* prior  = (float*)alloc((size_t)T_TOK * NHEAD * 4);
  f16* latent_h = (f16*)alloc((size_t)T_TOK * NHEAD * H_DIM * 2);  // 128 MiB

  // Logits buffer for a TOKEN QUARTER (64 MiB): total ws = 228.25 MiB — the
  // exact footprint proven to fit in R9 (ws_size is between 228.25 and
  // 292.25 MiB; R10's 292.25 MiB crashed). Shrink TQ if ws is tighter.
  int TQ = 2048;
  while (TQ > 256 && off + (size_t)TQ * NHEAD * V_DIM * 2 > ws_size) TQ >>= 1;
  f16* logits_q = (f16*)alloc((size_t)TQ * NHEAD * V_DIM * 2);

  // prep
  k_prior_conv<<<T_TOK / 4, 256, 0, stream>>>(hidden, prior_w, prior_b, prior,
                                              hidden_h);
  k_transpose<<<dim3(NHEAD * H_DIM / 64, H_DIM / 64), 256, 0, stream>>>(
      latent_w, lw_t, H_DIM, NHEAD * H_DIM);
  k_transpose<<<dim3(V_DIM / 64, H_DIM / 64), 256, 0, stream>>>(
      output_w, ow_t, H_DIM, V_DIM);

  // GEMM1: latent = tanh(hidden @ latent_w + b), single launch, 4 n-strips of
  // 2048 via grid.z — per strip B (4 MiB) L2-resident per XCD.
  k_gemm<1><<<dim3(8, T_TOK / 256, 4), 512, 0, stream>>>(
      hidden_h, lw_t, latent_b, latent_h, T_TOK, NHEAD * H_DIM, H_DIM);

  // G2 + softmax in token-quarters sharing ONE 64 MiB logits buffer: the live
  // intermediate stays L3-resident -> SM reads are L3 hits; most G2 writes
  // never drain to HBM (re-dirtied in place each quarter).
  const int nq = T_TOK / TQ;
  for (int s = 0; s < nq; ++s) {
    const int MR = TQ * NHEAD;  // rows per quarter (16384 at TQ=2048)
    k_gemm<0><<<dim3(8, MR / 256, 1), 512, 0, stream>>>(
        latent_h + (size_t)s * MR * H_DIM, ow_t, output_b, logits_q, MR, V_DIM,
        H_DIM);
    k_softmax<<<TQ, 256, 0, stream>>>(logits_q, prior, out, s * TQ);
  }
}

// Round 12
// 542.736 us; speedup vs baseline: 1.1039x; 1.1017x over previous
//
#include <hip/hip_runtime.h>
#include <hip/hip_bf16.h>
#include <stdint.h>

typedef _Float16 f16;
typedef _Float16 f16x8 __attribute__((ext_vector_type(8)));
typedef _Float16 f16x4 __attribute__((ext_vector_type(4)));
typedef float f32x4 __attribute__((ext_vector_type(4)));

#define T_TOK 8192
#define H_DIM 1024
#define NHEAD 8
#define V_DIM 2048

// global -> LDS direct load, 16B per lane. LDS dest = wave-uniform base + lane*16.
__device__ __forceinline__ void gload16(const void* g, void* l) {
  __builtin_amdgcn_global_load_lds(
      (const __attribute__((address_space(1))) void*)(uintptr_t)g,
      (__attribute__((address_space(3))) void*)(unsigned)(uintptr_t)l,
      16, 0, 0);
}

__device__ __forceinline__ float fast_tanh(float x) {
  float xc = fminf(fmaxf(x, -12.f), 12.f);
  float e = __expf(2.f * xc);
  return (e - 1.f) / (e + 1.f);
}

// Stage one half-tile (128 rows x 64 f16 = 16KB) with 2 global_load_lds.
// LDS[row*128 + (chunk^(row&7))*16] = global[row][chunk*8..+8]
__device__ __forceinline__ void stage_half(const f16* __restrict__ gRowBase,
                                           char* ldsHalf, int tid, int sl8,
                                           int Kd) {
  const int srow = tid >> 3;
  char* wuni = ldsHalf + ((tid >> 6) << 10);  // wave-uniform base
  gload16(gRowBase + (size_t)srow * Kd + sl8, wuni);
  gload16(gRowBase + (size_t)(srow + 64) * Kd + sl8, wuni + 8192);
}

// ---------- 256x256x64 pipelined 4-phase GEMM, 16x16x32 MFMA ----------
// R3-proven kernel (0 bank conflicts, 74us @ M=16384 G2 shape) with strip-grid.
// 8 waves (2M x 4N), per-wave 128x64 out = acc[8][4] f32x4. Phase q = m-pair
// {2q,2q+1} x full K=64 (m201 quadrant scheme). af ping-pong one phase ahead;
// 1 barrier/phase; counted vmcnt(4) per K-tile (T4); setprio (T5).
// Grid (8, M/256, NS): NS strips of 2048 cols; per strip m-major XCD swizzle
// -> B-strip (4 MiB) L2-resident per XCD.
template <int TANH>
__global__ __launch_bounds__(512, 2) void k_gemm(const f16* __restrict__ A,
                                                 const f16* __restrict__ Bt,
                                                 const float* __restrict__ bias,
                                                 f16* __restrict__ C,
                                                 int M, int N, int K) {
  __shared__ __align__(16) f16 sA[2][16384];
  __shared__ __align__(16) f16 sB[2][16384];
  const int tid = threadIdx.x;
  const int lane = tid & 63;
  const int wid = tid >> 6;
  const int wr = wid >> 2, wc = wid & 3;
  const int id = blockIdx.y * 8 + blockIdx.x;
  const int cpx = gridDim.y;
  const int sw = (id & 7) * cpx + (id >> 3);
  const int m0 = (sw >> 3) * 256;
  const int n0 = blockIdx.z * 2048 + (sw & 7) * 256;
  const int NT = K >> 6;  // NT even
  const int sl8 = ((tid & 7) ^ ((tid >> 3) & 7)) << 3;  // staging src col (f16)
  const int lo15 = lane & 15;
  // frag read offsets: slot = chunk ^ (row&7); row&7 == lane&7 since row=..+lo15
  const int offk0 = lo15 * 128 + (((lane >> 4)) ^ (lane & 7)) * 16;
  const int offk1 = lo15 * 128 + ((4 + (lane >> 4)) ^ (lane & 7)) * 16;

  const f16* Ag = A + (size_t)m0 * K;
  const f16* Bg = Bt + (size_t)n0 * K;
  char* sAb = (char*)&sA[0][0];
  char* sBb = (char*)&sB[0][0];

  // prologue: tile0 A+B -> buf0, tile1 B -> buf1
  stage_half(Ag, sAb, tid, sl8, K);
  stage_half(Ag + (size_t)128 * K, sAb + 16384, tid, sl8, K);
  stage_half(Bg, sBb, tid, sl8, K);
  stage_half(Bg + (size_t)128 * K, sBb + 16384, tid, sl8, K);
  stage_half(Bg + 64, sBb + 32768, tid, sl8, K);
  stage_half(Bg + (size_t)128 * K + 64, sBb + 32768 + 16384, tid, sl8, K);
  asm volatile("s_waitcnt vmcnt(4)" ::: "memory");  // tile0 A+B resident
  __builtin_amdgcn_s_barrier();
  __builtin_amdgcn_sched_barrier(0);

  f32x4 acc[8][4] = {};
  f16x8 af0[4], af1[4], bf[4][2];

#define LDA_SET(dst, base, q)                                                  \
  {                                                                            \
    dst[0] = *(const f16x8*)((base) + wr * 16384 + (2 * (q) + 0) * 2048 + offk0); \
    dst[1] = *(const f16x8*)((base) + wr * 16384 + (2 * (q) + 0) * 2048 + offk1); \
    dst[2] = *(const f16x8*)((base) + wr * 16384 + (2 * (q) + 1) * 2048 + offk0); \
    dst[3] = *(const f16x8*)((base) + wr * 16384 + (2 * (q) + 1) * 2048 + offk1); \
  }
#define LDB(base)                                                              \
  {                                                                            \
    _Pragma("unroll") for (int ni = 0; ni < 4; ++ni) {                         \
      bf[ni][0] = *(const f16x8*)((base) + wc * 8192 + ni * 2048 + offk0);     \
      bf[ni][1] = *(const f16x8*)((base) + wc * 8192 + ni * 2048 + offk1);     \
    }                                                                          \
  }
#define MFMA16(q, S)                                                           \
  {                                                                            \
    __builtin_amdgcn_s_setprio(1);                                             \
    _Pragma("unroll") for (int ni = 0; ni < 4; ++ni) {                         \
      acc[2 * (q) + 0][ni] = __builtin_amdgcn_mfma_f32_16x16x32_f16(           \
          S[0], bf[ni][0], acc[2 * (q) + 0][ni], 0, 0, 0);                     \
      acc[2 * (q) + 0][ni] = __builtin_amdgcn_mfma_f32_16x16x32_f16(           \
          S[1], bf[ni][1], acc[2 * (q) + 0][ni], 0, 0, 0);                     \
      acc[2 * (q) + 1][ni] = __builtin_amdgcn_mfma_f32_16x16x32_f16(           \
          S[2], bf[ni][0], acc[2 * (q) + 1][ni], 0, 0, 0);                     \
      acc[2 * (q) + 1][ni] = __builtin_amdgcn_mfma_f32_16x16x32_f16(           \
          S[3], bf[ni][1], acc[2 * (q) + 1][ni], 0, 0, 0);                     \
    }                                                                          \
    __builtin_amdgcn_s_setprio(0);                                             \
  }

  // preload phase-0 fragments of tile 0
  LDA_SET(af0, sAb, 0);

#define HALF(tt, bc)                                                           \
  {                                                                            \
    const char* cA = sAb + (bc)*32768;                                         \
    const char* cB = sBb + (bc)*32768;                                         \
    char* nA = sAb + ((bc) ^ 1) * 32768;                                       \
    char* nB = sBb + (bc)*32768;                                               \
    const int ktA = ((tt) + 1) << 6, ktB = ((tt) + 2) << 6;                    \
    const bool doA = (tt) + 1 < NT, doB = (tt) + 2 < NT;                       \
    /* ph0: B regs + af(ph1) issue, MFMA ph0 */                                \
    if (doA) stage_half(Ag + ktA, nA, tid, sl8, K);                            \
    LDB(cB);                                                                   \
    LDA_SET(af1, cA, 1);                                                       \
    __builtin_amdgcn_sched_barrier(0);                                         \
    MFMA16(0, af0);                                                            \
    __builtin_amdgcn_s_barrier();                                              \
    /* ph1 */                                                                  \
    if (doA) stage_half(Ag + (size_t)128 * K + ktA, nA + 16384, tid, sl8, K);  \
    LDA_SET(af0, cA, 2);                                                       \
    __builtin_amdgcn_sched_barrier(0);                                         \
    MFMA16(1, af1);                                                            \
    __builtin_amdgcn_s_barrier();                                              \
    /* ph2 */                                                                  \
    if (doB) stage_half(Bg + ktB, nB, tid, sl8, K);                            \
    LDA_SET(af1, cA, 3);                                                       \
    __builtin_amdgcn_sched_barrier(0);                                         \
    MFMA16(2, af0);                                                            \
    __builtin_amdgcn_s_barrier();                                              \
    /* ph3: counted vmcnt; preload next tile ph0 after barrier */              \
    if (doB) stage_half(Bg + (size_t)128 * K + ktB, nB + 16384, tid, sl8, K);  \
    if (doB) {                                                                 \
      asm volatile("s_waitcnt vmcnt(4)" ::: "memory");                         \
    } else {                                                                   \
      asm volatile("s_waitcnt vmcnt(0)" ::: "memory");                         \
    }                                                                          \
    __builtin_amdgcn_s_barrier();                                              \
    __builtin_amdgcn_sched_barrier(0);                                         \
    if (doA) LDA_SET(af0, sAb + ((bc) ^ 1) * 32768, 0);                        \
    __builtin_amdgcn_sched_barrier(0);                                         \
    MFMA16(3, af1);                                                            \
  }

#pragma unroll 1
  for (int T = 0; T < NT; T += 2) {
    HALF(T, 0);
    HALF(T + 1, 1);
  }
#undef HALF
#undef LDA_SET
#undef LDB
#undef MFMA16

  // epilogue: 16x16 D layout: col = lane&15, row = (lane>>4)*4 + reg.
  // Row-outer / ni-inner so 4 stores per 128B line are consecutive (WC-merge).
  const int crow = m0 + wr * 128 + ((lane >> 4) << 2);
  const int ccol0 = n0 + wc * 64 + lo15;
  float bv[4];
#pragma unroll
  for (int ni = 0; ni < 4; ++ni) bv[ni] = bias[ccol0 + ni * 16];
#pragma unroll
  for (int mi = 0; mi < 8; ++mi) {
#pragma unroll
    for (int r = 0; r < 4; ++r) {
      f16* Crow = C + (size_t)(crow + mi * 16 + r) * N;
#pragma unroll
      for (int ni = 0; ni < 4; ++ni) {
        float v = acc[mi][ni][r] + bv[ni];
        if (TANH) v = fast_tanh(v);
        Crow[ccol0 + ni * 16] = (f16)v;
      }
    }
  }
}

// ---------- fp32 [R][C] -> fp16 [C][R] transpose-convert, 64x64 tiles -------
__global__ __launch_bounds__(256) void k_transpose(const float* __restrict__ in,
                                                   f16* __restrict__ out,
                                                   int R, int C) {
  __shared__ f16 tile[64][66];
  const int c0 = blockIdx.x * 64, r0 = blockIdx.y * 64;
  const int tid = threadIdx.x;
  const int tr = tid >> 4;          // 0..15
  const int tc4 = (tid & 15) * 4;   // 0..60
#pragma unroll
  for (int i = 0; i < 4; ++i) {
    const int r = tr + i * 16;
    const float4 v = *(const float4*)&in[(size_t)(r0 + r) * C + c0 + tc4];
    tile[tc4 + 0][r] = (f16)v.x;
    tile[tc4 + 1][r] = (f16)v.y;
    tile[tc4 + 2][r] = (f16)v.z;
    tile[tc4 + 3][r] = (f16)v.w;
  }
  __syncthreads();
  const int oc = tid >> 2;          // 0..63
  const int or4 = (tid & 3) * 16;   // 0,16,32,48
#pragma unroll
  for (int i = 0; i < 4; ++i) {
    f16x4 w;
    w[0] = tile[oc][or4 + i * 4 + 0];
    w[1] = tile[oc][or4 + i * 4 + 1];
    w[2] = tile[oc][or4 + i * 4 + 2];
    w[3] = tile[oc][or4 + i * 4 + 3];
    *(f16x4*)&out[(size_t)(c0 + oc) * R + r0 + or4 + i * 4] = w;
  }
}

// ---------- fused prior + hidden->f16 convert (one pass over hidden) --------
__global__ __launch_bounds__(256) void k_prior_conv(const float* __restrict__ hidden,
                                                    const float* __restrict__ pw,
                                                    const float* __restrict__ pb,
                                                    float* __restrict__ prior,
                                                    f16* __restrict__ hidden_h) {
  const int wid = threadIdx.x >> 6, lane = threadIdx.x & 63;
  const int t = blockIdx.x * 4 + wid;
  const float* hrow = hidden + (size_t)t * H_DIM;
  f16* orow = hidden_h + (size_t)t * H_DIM;
  float acc[NHEAD] = {0.f, 0.f, 0.f, 0.f, 0.f, 0.f, 0.f, 0.f};
#pragma unroll
  for (int i = 0; i < 4; ++i) {
    const int k = i * 256 + lane * 4;
    const float4 v = *(const float4*)(hrow + k);
    f16x4 o;
    o[0] = (f16)v.x; o[1] = (f16)v.y; o[2] = (f16)v.z; o[3] = (f16)v.w;
    *(f16x4*)(orow + k) = o;
    const float vv[4] = {v.x, v.y, v.z, v.w};
#pragma unroll
    for (int j = 0; j < 4; ++j) {
      const float* wr = pw + (size_t)(k + j) * NHEAD;
#pragma unroll
      for (int h = 0; h < NHEAD; ++h) acc[h] += vv[j] * wr[h];
    }
  }
#pragma unroll
  for (int h = 0; h < NHEAD; ++h) {
#pragma unroll
    for (int off = 32; off >= 1; off >>= 1) acc[h] += __shfl_xor(acc[h], off);
  }
  if (lane == 0) {
    float p[NHEAD], s = 0.f;
#pragma unroll
    for (int h = 0; h < NHEAD; ++h) {
      p[h] = 1.f / (1.f + __expf(-(acc[h] + pb[h])));
      s += p[h];
    }
    float inv = 1.f / (s + 1e-8f);
#pragma unroll
    for (int h = 0; h < NHEAD; ++h) prior[t * NHEAD + h] = p[h] * inv;
  }
}

// ---------- block-per-token softmax (no max pass), chunk-local logits -------
__global__ __launch_bounds__(256) void k_softmax(const f16* __restrict__ logits,
                                                 const float* __restrict__ prior,
                                                 float* __restrict__ out,
                                                 int t0) {
  __shared__ float redsm[NHEAD * 4];
  const int tl = blockIdx.x;
  const int t = t0 + tl;
  const int tid = threadIdx.x, lane = tid & 63, wid = tid >> 6;
  const f16* base = logits + (size_t)tl * NHEAD * V_DIM + tid * 8;

  f16x8 x[NHEAD];
#pragma unroll
  for (int h = 0; h < NHEAD; ++h) x[h] = *(const f16x8*)(base + h * V_DIM);

  float xv[NHEAD][8];
  float sml[NHEAD];
#pragma unroll
  for (int h = 0; h < NHEAD; ++h) {
    float s = 0.f;
#pragma unroll
    for (int j = 0; j < 8; ++j) {
      xv[h][j] = __expf(fminf((float)x[h][j], 50.f));
      s += xv[h][j];
    }
    sml[h] = s;
  }
#pragma unroll
  for (int h = 0; h < NHEAD; ++h) {
#pragma unroll
    for (int off = 32; off >= 1; off >>= 1) sml[h] += __shfl_xor(sml[h], off);
  }
  if (lane == 0) {
#pragma unroll
    for (int h = 0; h < NHEAD; ++h) redsm[h * 4 + wid] = sml[h];
  }
  __syncthreads();

  float oa[8] = {0.f, 0.f, 0.f, 0.f, 0.f, 0.f, 0.f, 0.f};
#pragma unroll
  for (int h = 0; h < NHEAD; ++h) {
    const float s = redsm[h * 4 + 0] + redsm[h * 4 + 1] + redsm[h * 4 + 2] +
                    redsm[h * 4 + 3];
    const float coef = prior[t * NHEAD + h] / s;
#pragma unroll
    for (int j = 0; j < 8; ++j) oa[j] += coef * xv[h][j];
  }
  float4* op = (float4*)(out + (size_t)t * V_DIM + tid * 8);
  op[0] = make_float4(oa[0], oa[1], oa[2], oa[3]);
  op[1] = make_float4(oa[4], oa[5], oa[6], oa[7]);
}

extern "C" void kernel_launch(void* const* d_in, const int* in_sizes, int n_in,
                              void* d_out, int out_size, void* d_ws, size_t ws_size,
                              hipStream_t stream) {
  const float* hidden   = (const float*)d_in[0];
  const float* prior_w  = (const float*)d_in[1];
  const float* prior_b  = (const float*)d_in[2];
  const float* latent_w = (const float*)d_in[3];
  const float* latent_b = (const float*)d_in[4];
  const float* output_w = (const float*)d_in[5];
  const float* output_b = (const float*)d_in[6];
  float* out = (float*)d_out;

  char* ws = (char*)d_ws;
  size_t off = 0;
  auto alloc = [&](size_t bytes) -> void* {
    void* p = ws + off;
    off += (bytes + 255) & ~(size_t)255;
    return p;
  };
  f16* hidden_h = (f16*)alloc((size_t)T_TOK * H_DIM * 2);          // 16 MiB
  f16* lw_t     = (f16*)alloc((size_t)NHEAD * H_DIM * H_DIM * 2);  // 16 MiB
  f16* ow_t     = (f16*)alloc((size_t)V_DIM * H_DIM * 2);          // 4 MiB
  float* prior  = (float*)alloc((size_t)T_TOK * NHEAD * 4);

  // Streaming chunks: TC tokens per chunk; latent buffer REUSED across chunks
  // (dead after its G2 consumes it). TC=4096 -> latent 64 MiB + logits 128 MiB
  // + 36.25 fixed = 228.25 MiB (R8/R9-proven fit; ws < 292.25 per R10 crash).
  int TC = T_TOK / 2;
  while (TC > 256 &&
         off + (size_t)TC * NHEAD * H_DIM * 2 + 256 +
                 (size_t)TC * NHEAD * V_DIM * 2 >
             ws_size)
    TC >>= 1;
  f16* latent_c = (f16*)alloc((size_t)TC * NHEAD * H_DIM * 2);
  f16* logits_c = (f16*)alloc((size_t)TC * NHEAD * V_DIM * 2);

  // prep
  k_prior_conv<<<T_TOK / 4, 256, 0, stream>>>(hidden, prior_w, prior_b, prior,
                                              hidden_h);
  k_transpose<<<dim3(NHEAD * H_DIM / 64, H_DIM / 64), 256, 0, stream>>>(
      latent_w, lw_t, H_DIM, NHEAD * H_DIM);
  k_transpose<<<dim3(V_DIM / 64, H_DIM / 64), 256, 0, stream>>>(
      output_w, ow_t, H_DIM, V_DIM);

  const int nchunk = T_TOK / TC;
  for (int s = 0; s < nchunk; ++s) {
    // G1 chunk: latent = tanh(hidden @ latent_w + b); 4 n-strips via grid.z
    // (per strip B 4 MiB L2-resident per XCD). Output -> reused latent_c.
    k_gemm<1><<<dim3(8, TC / 256, 4), 512, 0, stream>>>(
        hidden_h + (size_t)s * TC * H_DIM, lw_t, latent_b, latent_c, TC,
        NHEAD * H_DIM, H_DIM);
    // G2 chunk: logits = latent @ output_w + b (single 2048-col strip).
    k_gemm<0><<<dim3(8, TC * NHEAD / 256, 1), 512, 0, stream>>>(
        latent_c, ow_t, output_b, logits_c, TC * NHEAD, V_DIM, H_DIM);
    // softmax + prior-weighted combine for this chunk's tokens.
    k_softmax<<<TC, 256, 0, stream>>>(logits_c, prior, out, s * TC);
  }
}

// Round 13
// 538.839 us; speedup vs baseline: 1.1119x; 1.0072x over previous
//
#include <hip/hip_runtime.h>
#include <hip/hip_bf16.h>
#include <stdint.h>

typedef _Float16 f16;
typedef _Float16 f16x8 __attribute__((ext_vector_type(8)));
typedef _Float16 f16x4 __attribute__((ext_vector_type(4)));
typedef float f32x4 __attribute__((ext_vector_type(4)));

#define T_TOK 8192
#define H_DIM 1024
#define NHEAD 8
#define V_DIM 2048

// global -> LDS direct load, 16B per lane. LDS dest = wave-uniform base + lane*16.
__device__ __forceinline__ void gload16(const void* g, void* l) {
  __builtin_amdgcn_global_load_lds(
      (const __attribute__((address_space(1))) void*)(uintptr_t)g,
      (__attribute__((address_space(3))) void*)(unsigned)(uintptr_t)l,
      16, 0, 0);
}

__device__ __forceinline__ float fast_tanh(float x) {
  float xc = fminf(fmaxf(x, -12.f), 12.f);
  float e = __expf(2.f * xc);
  return (e - 1.f) / (e + 1.f);
}

// Stage one half-tile (128 rows x 64 f16 = 16KB) with 2 global_load_lds.
// LDS[row*128 + (chunk^(row&7))*16] = global[row][chunk*8..+8]
__device__ __forceinline__ void stage_half(const f16* __restrict__ gRowBase,
                                           char* ldsHalf, int tid, int sl8,
                                           int Kd) {
  const int srow = tid >> 3;
  char* wuni = ldsHalf + ((tid >> 6) << 10);  // wave-uniform base
  gload16(gRowBase + (size_t)srow * Kd + sl8, wuni);
  gload16(gRowBase + (size_t)(srow + 64) * Kd + sl8, wuni + 8192);
}

// ---------- 256x256x64 pipelined 4-phase GEMM, 16x16x32 MFMA ----------
// R12-proven kernel (0 bank conflicts, 0.97 PF on G2). Inner loop untouched.
// MAP=0: grid (8, M/256, NS) — G2 mapping: per CU-round each XCD gets
//        4 m-rows x 8 n-tiles (B 4 MiB L2-exact).
// MAP=1: grid (8, 16, 4) [M=4096, N=8192] — 512 blocks, 2 CU-rounds. Per
//        round, XCDs 0-3 serve strip 2r, XCDs 4-7 strip 2r+1, each XCD
//        4 m-rows x 8 n-tiles -> A 2 MiB + B 4 MiB per XCD (G2's traffic
//        shape; fixes the dual-strip 8 MiB L2 thrash of the grid.z mapping).
template <int TANH, int MAP>
__global__ __launch_bounds__(512, 2) void k_gemm(const f16* __restrict__ A,
                                                 const f16* __restrict__ Bt,
                                                 const float* __restrict__ bias,
                                                 f16* __restrict__ C,
                                                 int M, int N, int K) {
  __shared__ __align__(16) f16 sA[2][16384];
  __shared__ __align__(16) f16 sB[2][16384];
  const int tid = threadIdx.x;
  const int lane = tid & 63;
  const int wid = tid >> 6;
  const int wr = wid >> 2, wc = wid & 3;
  int m0, n0;
  if (MAP == 1) {
    const int id = ((int)blockIdx.z * gridDim.y + blockIdx.y) * 8 + blockIdx.x;
    const int r = id >> 8;               // CU-round (0/1)
    const int x = id & 7;                // dispatch XCD
    const int j = (id >> 3) & 31;        // 32 blocks per XCD per round
    const int strip = r * 2 + (x >> 2);  // XCD half -> strip
    m0 = (((x & 3) << 2) + (j >> 3)) * 256;  // 16 m-rows
    n0 = strip * 2048 + (j & 7) * 256;       // 8 n-tiles per strip
  } else {
    const int id = blockIdx.y * 8 + blockIdx.x;
    const int cpx = gridDim.y;
    const int sw = (id & 7) * cpx + (id >> 3);
    m0 = (sw >> 3) * 256;
    n0 = blockIdx.z * 2048 + (sw & 7) * 256;
  }
  const int NT = K >> 6;  // NT even
  const int sl8 = ((tid & 7) ^ ((tid >> 3) & 7)) << 3;  // staging src col (f16)
  const int lo15 = lane & 15;
  const int offk0 = lo15 * 128 + (((lane >> 4)) ^ (lane & 7)) * 16;
  const int offk1 = lo15 * 128 + ((4 + (lane >> 4)) ^ (lane & 7)) * 16;

  const f16* Ag = A + (size_t)m0 * K;
  const f16* Bg = Bt + (size_t)n0 * K;
  char* sAb = (char*)&sA[0][0];
  char* sBb = (char*)&sB[0][0];

  // prologue: tile0 A+B -> buf0, tile1 B -> buf1
  stage_half(Ag, sAb, tid, sl8, K);
  stage_half(Ag + (size_t)128 * K, sAb + 16384, tid, sl8, K);
  stage_half(Bg, sBb, tid, sl8, K);
  stage_half(Bg + (size_t)128 * K, sBb + 16384, tid, sl8, K);
  stage_half(Bg + 64, sBb + 32768, tid, sl8, K);
  stage_half(Bg + (size_t)128 * K + 64, sBb + 32768 + 16384, tid, sl8, K);
  asm volatile("s_waitcnt vmcnt(4)" ::: "memory");  // tile0 A+B resident
  __builtin_amdgcn_s_barrier();
  __builtin_amdgcn_sched_barrier(0);

  f32x4 acc[8][4] = {};
  f16x8 af0[4], af1[4], bf[4][2];

#define LDA_SET(dst, base, q)                                                  \
  {                                                                            \
    dst[0] = *(const f16x8*)((base) + wr * 16384 + (2 * (q) + 0) * 2048 + offk0); \
    dst[1] = *(const f16x8*)((base) + wr * 16384 + (2 * (q) + 0) * 2048 + offk1); \
    dst[2] = *(const f16x8*)((base) + wr * 16384 + (2 * (q) + 1) * 2048 + offk0); \
    dst[3] = *(const f16x8*)((base) + wr * 16384 + (2 * (q) + 1) * 2048 + offk1); \
  }
#define LDB(base)                                                              \
  {                                                                            \
    _Pragma("unroll") for (int ni = 0; ni < 4; ++ni) {                         \
      bf[ni][0] = *(const f16x8*)((base) + wc * 8192 + ni * 2048 + offk0);     \
      bf[ni][1] = *(const f16x8*)((base) + wc * 8192 + ni * 2048 + offk1);     \
    }                                                                          \
  }
#define MFMA16(q, S)                                                           \
  {                                                                            \
    __builtin_amdgcn_s_setprio(1);                                             \
    _Pragma("unroll") for (int ni = 0; ni < 4; ++ni) {                         \
      acc[2 * (q) + 0][ni] = __builtin_amdgcn_mfma_f32_16x16x32_f16(           \
          S[0], bf[ni][0], acc[2 * (q) + 0][ni], 0, 0, 0);                     \
      acc[2 * (q) + 0][ni] = __builtin_amdgcn_mfma_f32_16x16x32_f16(           \
          S[1], bf[ni][1], acc[2 * (q) + 0][ni], 0, 0, 0);                     \
      acc[2 * (q) + 1][ni] = __builtin_amdgcn_mfma_f32_16x16x32_f16(           \
          S[2], bf[ni][0], acc[2 * (q) + 1][ni], 0, 0, 0);                     \
      acc[2 * (q) + 1][ni] = __builtin_amdgcn_mfma_f32_16x16x32_f16(           \
          S[3], bf[ni][1], acc[2 * (q) + 1][ni], 0, 0, 0);                     \
    }                                                                          \
    __builtin_amdgcn_s_setprio(0);                                             \
  }

  // preload phase-0 fragments of tile 0
  LDA_SET(af0, sAb, 0);

#define HALF(tt, bc)                                                           \
  {                                                                            \
    const char* cA = sAb + (bc)*32768;                                         \
    const char* cB = sBb + (bc)*32768;                                         \
    char* nA = sAb + ((bc) ^ 1) * 32768;                                       \
    char* nB = sBb + (bc)*32768;                                               \
    const int ktA = ((tt) + 1) << 6, ktB = ((tt) + 2) << 6;                    \
    const bool doA = (tt) + 1 < NT, doB = (tt) + 2 < NT;                       \
    /* ph0: B regs + af(ph1) issue, MFMA ph0 */                                \
    if (doA) stage_half(Ag + ktA, nA, tid, sl8, K);                            \
    LDB(cB);                                                                   \
    LDA_SET(af1, cA, 1);                                                       \
    __builtin_amdgcn_sched_barrier(0);                                         \
    MFMA16(0, af0);                                                            \
    __builtin_amdgcn_s_barrier();                                              \
    /* ph1 */                                                                  \
    if (doA) stage_half(Ag + (size_t)128 * K + ktA, nA + 16384, tid, sl8, K);  \
    LDA_SET(af0, cA, 2);                                                       \
    __builtin_amdgcn_sched_barrier(0);                                         \
    MFMA16(1, af1);                                                            \
    __builtin_amdgcn_s_barrier();                                              \
    /* ph2 */                                                                  \
    if (doB) stage_half(Bg + ktB, nB, tid, sl8, K);                            \
    LDA_SET(af1, cA, 3);                                                       \
    __builtin_amdgcn_sched_barrier(0);                                         \
    MFMA16(2, af0);                                                            \
    __builtin_amdgcn_s_barrier();                                              \
    /* ph3: counted vmcnt; preload next tile ph0 after barrier */              \
    if (doB) stage_half(Bg + (size_t)128 * K + ktB, nB + 16384, tid, sl8, K);  \
    if (doB) {                                                                 \
      asm volatile("s_waitcnt vmcnt(4)" ::: "memory");                         \
    } else {                                                                   \
      asm volatile("s_waitcnt vmcnt(0)" ::: "memory");                         \
    }                                                                          \
    __builtin_amdgcn_s_barrier();                                              \
    __builtin_amdgcn_sched_barrier(0);                                         \
    if (doA) LDA_SET(af0, sAb + ((bc) ^ 1) * 32768, 0);                        \
    __builtin_amdgcn_sched_barrier(0);                                         \
    MFMA16(3, af1);                                                            \
  }

#pragma unroll 1
  for (int T = 0; T < NT; T += 2) {
    HALF(T, 0);
    HALF(T + 1, 1);
  }
#undef HALF
#undef LDA_SET
#undef LDB
#undef MFMA16

  // epilogue: 16x16 D layout: col = lane&15, row = (lane>>4)*4 + reg.
  const int crow = m0 + wr * 128 + ((lane >> 4) << 2);
  const int ccol0 = n0 + wc * 64 + lo15;
  float bv[4];
#pragma unroll
  for (int ni = 0; ni < 4; ++ni) bv[ni] = bias[ccol0 + ni * 16];
#pragma unroll
  for (int mi = 0; mi < 8; ++mi) {
#pragma unroll
    for (int r = 0; r < 4; ++r) {
      f16* Crow = C + (size_t)(crow + mi * 16 + r) * N;
#pragma unroll
      for (int ni = 0; ni < 4; ++ni) {
        float v = acc[mi][ni][r] + bv[ni];
        if (TANH) v = fast_tanh(v);
        Crow[ccol0 + ni * 16] = (f16)v;
      }
    }
  }
}

// ---------- fp32 [R][C] -> fp16 [C][R] transpose-convert, 64x64 tiles -------
__global__ __launch_bounds__(256) void k_transpose(const float* __restrict__ in,
                                                   f16* __restrict__ out,
                                                   int R, int C) {
  __shared__ f16 tile[64][66];
  const int c0 = blockIdx.x * 64, r0 = blockIdx.y * 64;
  const int tid = threadIdx.x;
  const int tr = tid >> 4;          // 0..15
  const int tc4 = (tid & 15) * 4;   // 0..60
#pragma unroll
  for (int i = 0; i < 4; ++i) {
    const int r = tr + i * 16;
    const float4 v = *(const float4*)&in[(size_t)(r0 + r) * C + c0 + tc4];
    tile[tc4 + 0][r] = (f16)v.x;
    tile[tc4 + 1][r] = (f16)v.y;
    tile[tc4 + 2][r] = (f16)v.z;
    tile[tc4 + 3][r] = (f16)v.w;
  }
  __syncthreads();
  const int oc = tid >> 2;          // 0..63
  const int or4 = (tid & 3) * 16;   // 0,16,32,48
#pragma unroll
  for (int i = 0; i < 4; ++i) {
    f16x4 w;
    w[0] = tile[oc][or4 + i * 4 + 0];
    w[1] = tile[oc][or4 + i * 4 + 1];
    w[2] = tile[oc][or4 + i * 4 + 2];
    w[3] = tile[oc][or4 + i * 4 + 3];
    *(f16x4*)&out[(size_t)(c0 + oc) * R + r0 + or4 + i * 4] = w;
  }
}

// ---------- fused prior + hidden->f16 convert (one pass over hidden) --------
__global__ __launch_bounds__(256) void k_prior_conv(const float* __restrict__ hidden,
                                                    const float* __restrict__ pw,
                                                    const float* __restrict__ pb,
                                                    float* __restrict__ prior,
                                                    f16* __restrict__ hidden_h) {
  const int wid = threadIdx.x >> 6, lane = threadIdx.x & 63;
  const int t = blockIdx.x * 4 + wid;
  const float* hrow = hidden + (size_t)t * H_DIM;
  f16* orow = hidden_h + (size_t)t * H_DIM;
  float acc[NHEAD] = {0.f, 0.f, 0.f, 0.f, 0.f, 0.f, 0.f, 0.f};
#pragma unroll
  for (int i = 0; i < 4; ++i) {
    const int k = i * 256 + lane * 4;
    const float4 v = *(const float4*)(hrow + k);
    f16x4 o;
    o[0] = (f16)v.x; o[1] = (f16)v.y; o[2] = (f16)v.z; o[3] = (f16)v.w;
    *(f16x4*)(orow + k) = o;
    const float vv[4] = {v.x, v.y, v.z, v.w};
#pragma unroll
    for (int j = 0; j < 4; ++j) {
      const float* wr = pw + (size_t)(k + j) * NHEAD;
#pragma unroll
      for (int h = 0; h < NHEAD; ++h) acc[h] += vv[j] * wr[h];
    }
  }
#pragma unroll
  for (int h = 0; h < NHEAD; ++h) {
#pragma unroll
    for (int off = 32; off >= 1; off >>= 1) acc[h] += __shfl_xor(acc[h], off);
  }
  if (lane == 0) {
    float p[NHEAD], s = 0.f;
#pragma unroll
    for (int h = 0; h < NHEAD; ++h) {
      p[h] = 1.f / (1.f + __expf(-(acc[h] + pb[h])));
      s += p[h];
    }
    float inv = 1.f / (s + 1e-8f);
#pragma unroll
    for (int h = 0; h < NHEAD; ++h) prior[t * NHEAD + h] = p[h] * inv;
  }
}

// ---------- block-per-token softmax (no max pass), chunk-local logits -------
__global__ __launch_bounds__(256) void k_softmax(const f16* __restrict__ logits,
                                                 const float* __restrict__ prior,
                                                 float* __restrict__ out,
                                                 int t0) {
  __shared__ float redsm[NHEAD * 4];
  const int tl = blockIdx.x;
  const int t = t0 + tl;
  const int tid = threadIdx.x, lane = tid & 63, wid = tid >> 6;
  const f16* base = logits + (size_t)tl * NHEAD * V_DIM + tid * 8;

  f16x8 x[NHEAD];
#pragma unroll
  for (int h = 0; h < NHEAD; ++h) x[h] = *(const f16x8*)(base + h * V_DIM);

  float xv[NHEAD][8];
  float sml[NHEAD];
#pragma unroll
  for (int h = 0; h < NHEAD; ++h) {
    float s = 0.f;
#pragma unroll
    for (int j = 0; j < 8; ++j) {
      xv[h][j] = __expf(fminf((float)x[h][j], 50.f));
      s += xv[h][j];
    }
    sml[h] = s;
  }
#pragma unroll
  for (int h = 0; h < NHEAD; ++h) {
#pragma unroll
    for (int off = 32; off >= 1; off >>= 1) sml[h] += __shfl_xor(sml[h], off);
  }
  if (lane == 0) {
#pragma unroll
    for (int h = 0; h < NHEAD; ++h) redsm[h * 4 + wid] = sml[h];
  }
  __syncthreads();

  float oa[8] = {0.f, 0.f, 0.f, 0.f, 0.f, 0.f, 0.f, 0.f};
#pragma unroll
  for (int h = 0; h < NHEAD; ++h) {
    const float s = redsm[h * 4 + 0] + redsm[h * 4 + 1] + redsm[h * 4 + 2] +
                    redsm[h * 4 + 3];
    const float coef = prior[t * NHEAD + h] / s;
#pragma unroll
    for (int j = 0; j < 8; ++j) oa[j] += coef * xv[h][j];
  }
  float4* op = (float4*)(out + (size_t)t * V_DIM + tid * 8);
  op[0] = make_float4(oa[0], oa[1], oa[2], oa[3]);
  op[1] = make_float4(oa[4], oa[5], oa[6], oa[7]);
}

extern "C" void kernel_launch(void* const* d_in, const int* in_sizes, int n_in,
                              void* d_out, int out_size, void* d_ws, size_t ws_size,
                              hipStream_t stream) {
  const float* hidden   = (const float*)d_in[0];
  const float* prior_w  = (const float*)d_in[1];
  const float* prior_b  = (const float*)d_in[2];
  const float* latent_w = (const float*)d_in[3];
  const float* latent_b = (const float*)d_in[4];
  const float* output_w = (const float*)d_in[5];
  const float* output_b = (const float*)d_in[6];
  float* out = (float*)d_out;

  char* ws = (char*)d_ws;
  size_t off = 0;
  auto alloc = [&](size_t bytes) -> void* {
    void* p = ws + off;
    off += (bytes + 255) & ~(size_t)255;
    return p;
  };
  f16* hidden_h = (f16*)alloc((size_t)T_TOK * H_DIM * 2);          // 16 MiB
  f16* lw_t     = (f16*)alloc((size_t)NHEAD * H_DIM * H_DIM * 2);  // 16 MiB
  f16* ow_t     = (f16*)alloc((size_t)V_DIM * H_DIM * 2);          // 4 MiB
  float* prior  = (float*)alloc((size_t)T_TOK * NHEAD * 4);

  // Streaming chunks: TC tokens per chunk; latent buffer reused across chunks.
  // TC=4096 -> 228.25 MiB total (R12-proven fit).
  int TC = T_TOK / 2;
  while (TC > 256 &&
         off + (size_t)TC * NHEAD * H_DIM * 2 + 256 +
                 (size_t)TC * NHEAD * V_DIM * 2 >
             ws_size)
    TC >>= 1;
  f16* latent_c = (f16*)alloc((size_t)TC * NHEAD * H_DIM * 2);
  f16* logits_c = (f16*)alloc((size_t)TC * NHEAD * V_DIM * 2);

  // prep
  k_prior_conv<<<T_TOK / 4, 256, 0, stream>>>(hidden, prior_w, prior_b, prior,
                                              hidden_h);
  k_transpose<<<dim3(NHEAD * H_DIM / 64, H_DIM / 64), 256, 0, stream>>>(
      latent_w, lw_t, H_DIM, NHEAD * H_DIM);
  k_transpose<<<dim3(V_DIM / 64, H_DIM / 64), 256, 0, stream>>>(
      output_w, ow_t, H_DIM, V_DIM);

  const int nchunk = T_TOK / TC;
  for (int s = 0; s < nchunk; ++s) {
    // G1 chunk: latent = tanh(hidden @ latent_w + b).
    // TC=4096: MAP=1 round/strip split (per XCD: A 2 MiB + B 4 MiB, L2-exact).
    // Fallback TC: old grid.z mapping.
    if (TC == 4096) {
      k_gemm<1, 1><<<dim3(8, 16, 4), 512, 0, stream>>>(
          hidden_h + (size_t)s * TC * H_DIM, lw_t, latent_b, latent_c, TC,
          NHEAD * H_DIM, H_DIM);
    } else {
      k_gemm<1, 0><<<dim3(8, TC / 256, 4), 512, 0, stream>>>(
          hidden_h + (size_t)s * TC * H_DIM, lw_t, latent_b, latent_c, TC,
          NHEAD * H_DIM, H_DIM);
    }
    // G2 chunk: logits = latent @ output_w + b (single 2048-col strip).
    k_gemm<0, 0><<<dim3(8, TC * NHEAD / 256, 1), 512, 0, stream>>>(
        latent_c, ow_t, output_b, logits_c, TC * NHEAD, V_DIM, H_DIM);
    // softmax + prior-weighted combine for this chunk's tokens.
    k_softmax<<<TC, 256, 0, stream>>>(logits_c, prior, out, s * TC);
  }
}